// Round 12
// baseline (154.548 us; speedup 1.0000x reference)
//
#include <hip/hip_runtime.h>
#include <hip/hip_bf16.h>

#define S_LEN 2048
#define DM    1024
#define NH    16
#define DH    64
#define WIN   256
#define BATCH 2

using f32x4   = __attribute__((ext_vector_type(4))) float;
using bf16x8  = __attribute__((ext_vector_type(8))) short;
using ushort8 = __attribute__((ext_vector_type(8))) unsigned short;

static __device__ __forceinline__ unsigned short f2bf(float f) {
  unsigned int x = __float_as_uint(f);
  x += 0x7fffu + ((x >> 16) & 1u);           // RNE, finite inputs only
  return (unsigned short)(x >> 16);
}

// async global -> LDS: HW writes wave-uniform LDS base + lane*16
typedef const __attribute__((address_space(1))) void* gas_t;
typedef __attribute__((address_space(3))) void* las_t;
static __device__ __forceinline__ void gload16(const void* g, void* l) {
  __builtin_amdgcn_global_load_lds((gas_t)g, (las_t)l, 16, 0, 0);
}

// ---------------- fp32 -> bf16 convert: 4 weights + 3 inputs + absmax init ----------------
__global__ __launch_bounds__(256) void k_cvt_all(const float* __restrict__ w0,
                                                 const float* __restrict__ w1,
                                                 const float* __restrict__ w2,
                                                 const float* __restrict__ w3,
                                                 const float* __restrict__ q,
                                                 const float* __restrict__ k,
                                                 const float* __restrict__ v,
                                                 unsigned short* __restrict__ Wb,
                                                 unsigned short* __restrict__ qb,
                                                 unsigned short* __restrict__ kb,
                                                 unsigned short* __restrict__ vb,
                                                 unsigned int* __restrict__ absmax) {
  const int z = blockIdx.z;
  if (z == 0 && blockIdx.x == 0 && threadIdx.x == 0) *absmax = 0u;
  const float* src;
  unsigned short* dst;
  int n8;
  if (z < 4) {
    src = (z == 0) ? w0 : (z == 1) ? w1 : (z == 2) ? w2 : w3;
    dst = Wb + (size_t)z * DM * DM;
    n8 = (DM * DM) / 8;
  } else {
    src = (z == 4) ? q : (z == 5) ? k : v;
    dst = (z == 4) ? qb : (z == 5) ? kb : vb;
    n8 = (BATCH * S_LEN * DM) / 8;
  }
  int i = blockIdx.x * blockDim.x + threadIdx.x;
  int stride = gridDim.x * blockDim.x;
  for (; i < n8; i += stride) {
    float4 f0 = ((const float4*)src)[2 * i];
    float4 f1 = ((const float4*)src)[2 * i + 1];
    ushort8 u;
    u[0] = f2bf(f0.x); u[1] = f2bf(f0.y); u[2] = f2bf(f0.z); u[3] = f2bf(f0.w);
    u[4] = f2bf(f1.x); u[5] = f2bf(f1.y); u[6] = f2bf(f1.z); u[7] = f2bf(f1.w);
    ((ushort8*)dst)[i] = u;
  }
}

// ---------------- GEMM core: C[row,col] = sum_k A[row,k]*B[col,k] ----------------
// BM=BN=128, BK=32, 2-phase double-buffered, 32 KB LDS -> 4 blocks/CU.
// Swizzle for 64B rows: chunk ^= (row>>1)&3 (16B chunks; gives 2-way banks = free),
// applied inverse on the global source, forward on the LDS read (rule #21).
// swap: mfma(B,A) so acc regs span gcol -> vector stores.
// omode: 0 = f32 [B,S,DM] (swap, + optional |x| partial); 1 = bf16 [b,h,s,d] (swap);
//        2 = bf16 [b,h,d,s] (no swap). Runtime params keep ONE LDS instance (round-8 lesson).
__device__ __forceinline__ void gemm128_core(const unsigned short* __restrict__ A,
                                             const unsigned short* __restrict__ Bw,
                                             void* __restrict__ Cptr, float oscale,
                                             int omode, bool swap, int R0, int C0,
                                             float* __restrict__ partials, int pbid) {
  __shared__ unsigned short As[2][128][32];   // 16 KB
  __shared__ unsigned short Bs[2][128][32];   // 16 KB
  __shared__ float red[4];
  const int tid = threadIdx.x, lane = tid & 63, w = tid >> 6;
  const int wr = w >> 1, wc = w & 1;

  // staging: lane covers (row = w*16 + lane/4 [+64 for call 1], chunk = lane&3),
  // source chunk = chunk ^ ((row>>1)&3) = (lane&3) ^ ((lane>>3)&3)
  const int s_row = w * 16 + (lane >> 2);
  const int s_col = ((lane & 3) ^ ((lane >> 3) & 3)) << 3;   // elements
  // read: element offset within row for this lane's k-slice (chunk ^ (row>>1)&3)
  const int rbyte = (((lane >> 4) ^ ((lane >> 1) & 3)) << 4);

  f32x4 z = {0.f, 0.f, 0.f, 0.f};
  f32x4 acc[4][4];
#pragma unroll
  for (int i = 0; i < 4; ++i)
#pragma unroll
    for (int j = 0; j < 4; ++j) acc[i][j] = z;

  unsigned short* Af0 = &As[0][0][0];
  unsigned short* Bf0 = &Bs[0][0][0];

#define STAGE_G(buf, k0) do {                                                      \
    unsigned short* Ad = Af0 + (buf) * 4096 + w * 512;                             \
    unsigned short* Bd = Bf0 + (buf) * 4096 + w * 512;                             \
    gload16(A  + (size_t)(R0 + s_row) * DM + (k0) + s_col, Ad);                    \
    gload16(A  + (size_t)(R0 + 64 + s_row) * DM + (k0) + s_col, Ad + 2048);        \
    gload16(Bw + (size_t)(C0 + s_row) * DM + (k0) + s_col, Bd);                    \
    gload16(Bw + (size_t)(C0 + 64 + s_row) * DM + (k0) + s_col, Bd + 2048);        \
  } while (0)

  STAGE_G(0, 0);
  __syncthreads();

  for (int t = 0; t < 32; ++t) {
    const int cur = t & 1;
    if (t + 1 < 32) STAGE_G(cur ^ 1, (t + 1) * 32);

    const char* Af = (const char*)(Af0 + cur * 4096);
    const char* Bf = (const char*)(Bf0 + cur * 4096);
    bf16x8 av[4], bv[4];
#pragma unroll
    for (int i = 0; i < 4; ++i) {
      av[i] = *(const bf16x8*)(Af + (64 * wr + 16 * i + (lane & 15)) * 64 + rbyte);
      bv[i] = *(const bf16x8*)(Bf + (64 * wc + 16 * i + (lane & 15)) * 64 + rbyte);
    }
    if (swap) {
#pragma unroll
      for (int i = 0; i < 4; ++i)
#pragma unroll
        for (int j = 0; j < 4; ++j)
          acc[i][j] = __builtin_amdgcn_mfma_f32_16x16x32_bf16(bv[j], av[i], acc[i][j], 0, 0, 0);
    } else {
#pragma unroll
      for (int i = 0; i < 4; ++i)
#pragma unroll
        for (int j = 0; j < 4; ++j)
          acc[i][j] = __builtin_amdgcn_mfma_f32_16x16x32_bf16(av[i], bv[j], acc[i][j], 0, 0, 0);
    }
    __syncthreads();   // drains vmcnt (next stage) + protects LDS
  }
#undef STAGE_G

  float s = 0.f;
#pragma unroll
  for (int i = 0; i < 4; ++i) {
#pragma unroll
    for (int j = 0; j < 4; ++j) {
      if (swap) {
        int grow  = R0 + 64 * wr + 16 * i + (lane & 15);
        int gcol0 = C0 + 64 * wc + 16 * j + 4 * (lane >> 4);
        if (omode == 0) {
          float4 st = {acc[i][j][0] * oscale, acc[i][j][1] * oscale,
                       acc[i][j][2] * oscale, acc[i][j][3] * oscale};
          s += fabsf(st.x) + fabsf(st.y) + fabsf(st.z) + fabsf(st.w);
          *(float4*)((float*)Cptr + (size_t)grow * DM + gcol0) = st;
        } else {
          int b = grow >> 11, ss = grow & (S_LEN - 1);
          int h = gcol0 >> 6, d0 = gcol0 & 63;
          ushort4 st = {f2bf(acc[i][j][0] * oscale), f2bf(acc[i][j][1] * oscale),
                        f2bf(acc[i][j][2] * oscale), f2bf(acc[i][j][3] * oscale)};
          *(ushort4*)((unsigned short*)Cptr + (((size_t)(b * NH + h) * S_LEN + ss) << 6) + d0) = st;
        }
      } else {
        int grow0 = R0 + 64 * wr + 16 * i + 4 * (lane >> 4);
        int gcol  = C0 + 64 * wc + 16 * j + (lane & 15);
        int b = grow0 >> 11, s0 = grow0 & (S_LEN - 1);
        int h = gcol >> 6, d = gcol & 63;
        ushort4 st = {f2bf(acc[i][j][0] * oscale), f2bf(acc[i][j][1] * oscale),
                      f2bf(acc[i][j][2] * oscale), f2bf(acc[i][j][3] * oscale)};
        *(ushort4*)((unsigned short*)Cptr + (((size_t)(b * NH + h) * DH + d) << 11) + s0) = st;
      }
    }
  }
  if (partials) {   // deterministic per-block |x| partial (fused abspart)
#pragma unroll
    for (int mk = 1; mk < 64; mk <<= 1) s += __shfl_xor(s, mk, 64);
    if (lane == 0) red[w] = s;
    __syncthreads();
    if (tid == 0) partials[pbid] = red[0] + red[1] + red[2] + red[3];
  }
}

// merged QKV: z selects operand set at runtime (one body -> one LDS instance; 768 blocks)
__global__ __launch_bounds__(256) void k_gemm_qkv(const unsigned short* __restrict__ qb,
                                                  const unsigned short* __restrict__ kb,
                                                  const unsigned short* __restrict__ vb,
                                                  const unsigned short* __restrict__ WbQ,
                                                  const unsigned short* __restrict__ WbK,
                                                  const unsigned short* __restrict__ WbV,
                                                  unsigned short* __restrict__ qh,
                                                  unsigned short* __restrict__ kh,
                                                  unsigned short* __restrict__ vt) {
  const unsigned short *A, *B;
  unsigned short* C;
  float sc;
  int om;
  bool sw;
  if (blockIdx.z == 0)      { A = qb; B = WbQ; C = qh; sc = 0.125f; om = 1; sw = true;  }
  else if (blockIdx.z == 1) { A = kb; B = WbK; C = kh; sc = 1.0f;   om = 1; sw = true;  }
  else                      { A = vb; B = WbV; C = vt; sc = 1.0f;   om = 2; sw = false; }
  gemm128_core(A, B, C, sc, om, sw, blockIdx.x * 128, blockIdx.y * 128, nullptr, 0);
}

__global__ __launch_bounds__(256) void k_gemm_out(const unsigned short* __restrict__ A,
                                                  const unsigned short* __restrict__ Bw,
                                                  float* __restrict__ C,
                                                  float* __restrict__ partials) {
  gemm128_core(A, Bw, C, 1.0f, 0, true, blockIdx.x * 128, blockIdx.y * 128,
               partials, blockIdx.x + gridDim.x * blockIdx.y);
}

// ---------------- full-matrix |scores| max (before masking) ----------------
// grid: (S/128, B*H). Q tile (128 rows) in registers; K chunks double-buffered via gload16+swizzle.
__global__ __launch_bounds__(256) void k_scoresmax(const unsigned short* __restrict__ qh,
                                                   const unsigned short* __restrict__ kh,
                                                   unsigned int* __restrict__ absmax) {
  __shared__ unsigned short Ks[2][128][64];
  const int tid = threadIdx.x, lane = tid & 63, w = tid >> 6;
  const size_t base = (size_t)blockIdx.y * S_LEN * DH;
  const unsigned short* Q = qh + base;
  const unsigned short* K = kh + base;
  const int q0 = blockIdx.x * 128;

  bf16x8 a[2][2];
#pragma unroll
  for (int rb = 0; rb < 2; ++rb) {
    const unsigned short* qr = Q + (size_t)(q0 + 32 * w + 16 * rb + (lane & 15)) * DH + 8 * (lane >> 4);
    a[rb][0] = *(const bf16x8*)qr;
    a[rb][1] = *(const bf16x8*)(qr + 32);
  }

  int srow[4], scol[4];
#pragma unroll
  for (int c = 0; c < 4; ++c) {
    srow[c] = c * 32 + w * 8 + (lane >> 3);
    scol[c] = ((lane & 7) ^ (srow[c] & 7)) << 3;
  }
  unsigned short* Kf0 = &Ks[0][0][0];
  const int cbb = 16 * (lane >> 4);

#define STAGE_K(buf, kc) do {                                                          \
    unsigned short* Kd = Kf0 + (buf) * 8192 + w * 512;                                 \
    _Pragma("unroll")                                                                  \
    for (int c = 0; c < 4; ++c)                                                        \
      gload16(K + (size_t)((kc) + srow[c]) * DH + scol[c], Kd + c * 2048);             \
  } while (0)

  STAGE_K(0, 0);
  __syncthreads();

  float m = 0.f;
  for (int t = 0; t < 16; ++t) {
    const int cur = t & 1;
    if (t + 1 < 16) STAGE_K(cur ^ 1, (t + 1) * 128);
    const char* Kf = (const char*)(Kf0 + cur * 8192);
#pragma unroll
    for (int cb = 0; cb < 8; ++cb) {
      int row = 16 * cb + (lane & 15);
      int sw = (row & 7) << 4;
      const char* rp = Kf + row * 128;
      bf16x8 b0 = *(const bf16x8*)(rp + (cbb ^ sw));
      bf16x8 b1 = *(const bf16x8*)(rp + ((cbb + 64) ^ sw));
#pragma unroll
      for (int rb = 0; rb < 2; ++rb) {
        f32x4 acc = {0.f, 0.f, 0.f, 0.f};
        acc = __builtin_amdgcn_mfma_f32_16x16x32_bf16(a[rb][0], b0, acc, 0, 0, 0);
        acc = __builtin_amdgcn_mfma_f32_16x16x32_bf16(a[rb][1], b1, acc, 0, 0, 0);
        m = fmaxf(m, fmaxf(fmaxf(fabsf(acc[0]), fabsf(acc[1])), fmaxf(fabsf(acc[2]), fabsf(acc[3]))));
      }
    }
    __syncthreads();
  }
#undef STAGE_K

#pragma unroll
  for (int mk = 1; mk < 64; mk <<= 1) m = fmaxf(m, __shfl_xor(m, mk, 64));
  __shared__ float red[4];
  if (lane == 0) red[w] = m;
  __syncthreads();
  if (threadIdx.x == 0)
    atomicMax(absmax, __float_as_uint(fmaxf(fmaxf(red[0], red[1]), fmaxf(red[2], red[3]))));
}

// ---------------- sliding-window attention, streaming 32-key tiles ----------------
// grid: (S/64, B*H). 4 waves; wave w owns q rows [Q0+16w, Q0+16w+15].
// Scores*invM are in [-1,1] -> no softmax max pass needed (exp() directly, masked -> 0).
// V comes pre-transposed: vt[b,h,d,s].
#define NT 10
__global__ __launch_bounds__(256) void k_attn(const unsigned short* __restrict__ qh,
                                              const unsigned short* __restrict__ kh,
                                              const unsigned short* __restrict__ vt,
                                              const unsigned int* __restrict__ absmax,
                                              unsigned short* __restrict__ attn_c) {
  __shared__ unsigned short Ks[2][32][72];    // 9216 B   K tile: [key][d]
  __shared__ unsigned short Vts[2][64][40];   // 10240 B  Vt tile: [d][key]
  __shared__ unsigned short Pl[4][16][40];    // 5120 B   per-wave P redistribution (80B row stride, b128-aligned)
  const int tid = threadIdx.x, lane = tid & 63, w = tid >> 6;
  const int bh = blockIdx.y, b = bh >> 4, h = bh & 15;
  const int Q0 = blockIdx.x * 64;
  const int kstart = Q0 - WIN;
  const size_t base = (size_t)bh * S_LEN * DH;
  const unsigned short* Kb = kh + base;
  const unsigned short* Vtb = vt + base;      // [d][s] rows of length S_LEN

  // staging coords (one ushort8 per thread per buffer)
  const int skrow = tid >> 3, skcol = (tid & 7) << 3;     // K: 32 rows x 64 d
  const int svd = tid >> 2, svcol = (tid & 3) << 3;       // Vt: 64 d x 32 keys

  const float invM = 1.0f / fmaxf(__uint_as_float(*absmax), 1.0f);
  const unsigned short* Qp = qh + base + (size_t)(Q0 + 16 * w + (lane & 15)) * DH + 8 * (lane >> 4);
  bf16x8 a0 = *(const bf16x8*)Qp;
  bf16x8 a1 = *(const bf16x8*)(Qp + 32);

  ushort8 rk, rv;
  ushort8 zz = {0, 0, 0, 0, 0, 0, 0, 0};
#define LOADT(T) do {                                                        \
    int kk = kstart + 32 * (T) + skrow;                                      \
    rk = (kk >= 0) ? *(const ushort8*)(Kb + (size_t)kk * DH + skcol) : zz;   \
    int kc = kstart + 32 * (T) + svcol;                                      \
    rv = (kc >= 0) ? *(const ushort8*)(Vtb + (size_t)svd * S_LEN + kc) : zz; \
  } while (0)
#define WRITET(buf) do {                                                     \
    *(ushort8*)&Ks[buf][skrow][skcol] = rk;                                  \
    *(ushort8*)&Vts[buf][svd][svcol] = rv;                                   \
  } while (0)

  LOADT(0);
  WRITET(0);
  __syncthreads();

  const int Tlo = w >> 1, Thi = (w >> 1) + 8;
  const int qrow = Q0 + 16 * w + 4 * (lane >> 4);
  float sm[4] = {0.f, 0.f, 0.f, 0.f};
  f32x4 z = {0.f, 0.f, 0.f, 0.f};
  f32x4 o[4];
#pragma unroll
  for (int i = 0; i < 4; ++i) o[i] = z;

  for (int T = 0; T < NT; ++T) {
    const int cur = T & 1;
    const bool act = (T >= Tlo) && (T <= Thi);
    if (T + 1 < NT) LOADT(T + 1);            // issue next-tile loads early
    if (act) {
      // QK^T: 32 keys, 2 col-blocks
      f32x4 p[2];
#pragma unroll
      for (int cb = 0; cb < 2; ++cb) {
        const unsigned short* kr = &Ks[cur][16 * cb + (lane & 15)][8 * (lane >> 4)];
        bf16x8 b0 = *(const bf16x8*)kr;
        bf16x8 b1 = *(const bf16x8*)(kr + 32);
        f32x4 a = z;
        a = __builtin_amdgcn_mfma_f32_16x16x32_bf16(a0, b0, a, 0, 0, 0);
        a = __builtin_amdgcn_mfma_f32_16x16x32_bf16(a1, b1, a, 0, 0, 0);
        p[cb] = a;
      }
      // mask + exp (no max needed: |s|<=1) + accumulate denominator + stash P
#pragma unroll
      for (int cb = 0; cb < 2; ++cb) {
        int kcol = kstart + 32 * T + 16 * cb + (lane & 15);
#pragma unroll
        for (int r = 0; r < 4; ++r) {
          int qq = qrow + r;
          bool ok = (kcol >= 0) && (kcol <= qq) && (kcol + WIN > qq);
          float e = ok ? __expf(p[cb][r] * invM) : 0.f;
          sm[r] += e;
          Pl[w][4 * (lane >> 4) + r][16 * cb + (lane & 15)] = f2bf(e);
        }
      }
    }
    __syncthreads();                         // Pl writes visible before A-frag read
    if (act) {
      // PV: one A-frag covers all 32 keys
      bf16x8 pa = *(const bf16x8*)&Pl[w][lane & 15][8 * (lane >> 4)];
#pragma unroll
      for (int dt = 0; dt < 4; ++dt) {
        bf16x8 bv = *(const bf16x8*)&Vts[cur][16 * dt + (lane & 15)][8 * (lane >> 4)];
        o[dt] = __builtin_amdgcn_mfma_f32_16x16x32_bf16(pa, bv, o[dt], 0, 0, 0);
      }
    }
    if (T + 1 < NT) WRITET((T + 1) & 1);     // write next tile into the other buffer
    __syncthreads();
  }

  // reduce denominator across the 16 column-lanes of each row group
#pragma unroll
  for (int r = 0; r < 4; ++r) {
#pragma unroll
    for (int mk = 1; mk < 16; mk <<= 1) sm[r] += __shfl_xor(sm[r], mk, 64);
    sm[r] = 1.0f / sm[r];
  }
#pragma unroll
  for (int dt = 0; dt < 4; ++dt) {
#pragma unroll
    for (int r = 0; r < 4; ++r) {
      int qq = qrow + r;
      float val = o[dt][r] * sm[r];
      attn_c[((size_t)(b * S_LEN + qq) << 10) + h * DH + 16 * dt + (lane & 15)] = f2bf(val);
    }
  }
#undef LOADT
#undef WRITET
}

// ---------------- final: denom from partials (every block, deterministic) + scale ----------------
__global__ __launch_bounds__(256) void k_scale_final(float* __restrict__ x,
                                                     const float* __restrict__ partials,
                                                     float invcnt, int n4) {
  __shared__ float red[4];
  float s = partials[threadIdx.x];           // blockDim == #partials == 256
#pragma unroll
  for (int mk = 1; mk < 64; mk <<= 1) s += __shfl_xor(s, mk, 64);
  if ((threadIdx.x & 63) == 0) red[threadIdx.x >> 6] = s;
  __syncthreads();
  float d = 1.0f / fmaxf((red[0] + red[1] + red[2] + red[3]) * invcnt, 1.0f);
  for (int i = blockIdx.x * blockDim.x + threadIdx.x; i < n4; i += gridDim.x * blockDim.x) {
    float4 f = ((float4*)x)[i];
    f.x *= d; f.y *= d; f.z *= d; f.w *= d;
    ((float4*)x)[i] = f;
  }
}

// ---------------- launch ----------------
extern "C" void kernel_launch(void* const* d_in, const int* in_sizes, int n_in,
                              void* d_out, int out_size, void* d_ws, size_t ws_size,
                              hipStream_t stream) {
  (void)in_sizes; (void)n_in; (void)out_size; (void)ws_size;
  const float* q  = (const float*)d_in[0];
  const float* k  = (const float*)d_in[1];
  const float* v  = (const float*)d_in[2];
  const float* WQ = (const float*)d_in[3];
  const float* WK = (const float*)d_in[4];
  const float* WV = (const float*)d_in[5];
  const float* WO = (const float*)d_in[6];

  const size_t HS = (size_t)BATCH * NH * S_LEN * DH;     // 4,194,304 elements
  unsigned short* qb     = (unsigned short*)d_ws;        // bf16 q input; reused as attn_c later
  unsigned short* kb     = qb + HS;
  unsigned short* vb     = kb + HS;
  unsigned short* qh     = vb + HS;
  unsigned short* kh     = qh + HS;
  unsigned short* vt     = kh + HS;                      // [b,h,d,s] bf16
  unsigned short* Wb     = vt + HS;                      // 4 x 1M bf16
  char* scal             = (char*)(Wb + 4 * (size_t)DM * DM);
  unsigned int* absmax   = (unsigned int*)scal;
  float* partials        = (float*)(scal + 16);          // 256 entries
  unsigned short* attn_c = qb;                           // alias: qb dead after QKV GEMM

  unsigned short* WbQ = Wb;
  unsigned short* WbK = Wb + (size_t)DM * DM;
  unsigned short* WbV = Wb + 2 * (size_t)DM * DM;
  unsigned short* WbO = Wb + 3 * (size_t)DM * DM;

  k_cvt_all<<<dim3(128, 1, 7), 256, 0, stream>>>(WQ, WK, WV, WO, q, k, v, Wb, qb, kb, vb, absmax);

  k_gemm_qkv<<<dim3(32, 8, 3), 256, 0, stream>>>(qb, kb, vb, WbQ, WbK, WbV, qh, kh, vt);

  k_scoresmax<<<dim3(16, 32), 256, 0, stream>>>(qh, kh, absmax);
  k_attn<<<dim3(32, 32), 256, 0, stream>>>(qh, kh, vt, absmax, attn_c);

  k_gemm_out<<<dim3(32, 8), 256, 0, stream>>>(attn_c, WbO, (float*)d_out, partials);

  k_scale_final<<<1024, 256, 0, stream>>>((float*)d_out, partials, 1.0f / (float)HS, (int)(HS / 4));
}

// Round 14
// 137.998 us; speedup vs baseline: 1.1199x; 1.1199x over previous
//
#include <hip/hip_runtime.h>
#include <hip/hip_bf16.h>

#define S_LEN 2048
#define DM    1024
#define NH    16
#define DH    64
#define WIN   256
#define BATCH 2

using f32x4   = __attribute__((ext_vector_type(4))) float;
using bf16x8  = __attribute__((ext_vector_type(8))) short;
using ushort8 = __attribute__((ext_vector_type(8))) unsigned short;

static __device__ __forceinline__ unsigned short f2bf(float f) {
  unsigned int x = __float_as_uint(f);
  x += 0x7fffu + ((x >> 16) & 1u);           // RNE, finite inputs only
  return (unsigned short)(x >> 16);
}

// async global -> LDS: HW writes wave-uniform LDS base + lane*16
typedef const __attribute__((address_space(1))) void* gas_t;
typedef __attribute__((address_space(3))) void* las_t;
static __device__ __forceinline__ void gload16(const void* g, void* l) {
  __builtin_amdgcn_global_load_lds((gas_t)g, (las_t)l, 16, 0, 0);
}

// ---------------- fp32 -> bf16 convert: 4 weights + 3 inputs + absmax init ----------------
__global__ __launch_bounds__(256) void k_cvt_all(const float* __restrict__ w0,
                                                 const float* __restrict__ w1,
                                                 const float* __restrict__ w2,
                                                 const float* __restrict__ w3,
                                                 const float* __restrict__ q,
                                                 const float* __restrict__ k,
                                                 const float* __restrict__ v,
                                                 unsigned short* __restrict__ Wb,
                                                 unsigned short* __restrict__ qb,
                                                 unsigned short* __restrict__ kb,
                                                 unsigned short* __restrict__ vb,
                                                 unsigned int* __restrict__ absmax) {
  const int z = blockIdx.z;
  if (z == 0 && blockIdx.x == 0 && threadIdx.x == 0) *absmax = 0u;
  const float* src;
  unsigned short* dst;
  int n8;
  if (z < 4) {
    src = (z == 0) ? w0 : (z == 1) ? w1 : (z == 2) ? w2 : w3;
    dst = Wb + (size_t)z * DM * DM;
    n8 = (DM * DM) / 8;
  } else {
    src = (z == 4) ? q : (z == 5) ? k : v;
    dst = (z == 4) ? qb : (z == 5) ? kb : vb;
    n8 = (BATCH * S_LEN * DM) / 8;
  }
  int i = blockIdx.x * blockDim.x + threadIdx.x;
  int stride = gridDim.x * blockDim.x;
  for (; i < n8; i += stride) {
    float4 f0 = ((const float4*)src)[2 * i];
    float4 f1 = ((const float4*)src)[2 * i + 1];
    ushort8 u;
    u[0] = f2bf(f0.x); u[1] = f2bf(f0.y); u[2] = f2bf(f0.z); u[3] = f2bf(f0.w);
    u[4] = f2bf(f1.x); u[5] = f2bf(f1.y); u[6] = f2bf(f1.z); u[7] = f2bf(f1.w);
    ((ushort8*)dst)[i] = u;
  }
}

// ---------------- GEMM core: C[row,col] = sum_k A[row,k]*B[col,k] ----------------
// BM=BN=128, BK=64, 2-phase double-buffered (round-11 proven best: 47 us, MfmaUtil 20%).
// global_load_lds staging, linear LDS, T2 swizzle (read byte ^= (row&7)<<4, source inverse).
// swap: mfma(B,A) so acc regs span gcol -> vector stores.
// omode: 0 = f32 [B,S,DM] (swap, + |x| partial); 1 = bf16 [b,h,s,d] (swap);
//        2 = bf16 [b,h,d,s] (no swap). Runtime params keep ONE LDS instance (round-8 lesson).
// BK=32 variant measured WORSE (59 us, round 12): fewer MFMA per barrier, 2x barriers.
__device__ __forceinline__ void gemm128_core(const unsigned short* __restrict__ A,
                                             const unsigned short* __restrict__ Bw,
                                             void* __restrict__ Cptr, float oscale,
                                             int omode, bool swap, int R0, int C0,
                                             float* __restrict__ partials, int pbid) {
  __shared__ unsigned short As[2][128][64];
  __shared__ unsigned short Bs[2][128][64];
  __shared__ float red[4];
  const int tid = threadIdx.x, lane = tid & 63, w = tid >> 6;
  const int wr = w >> 1, wc = w & 1;

  int srow[4], scol[4];
#pragma unroll
  for (int c = 0; c < 4; ++c) {
    srow[c] = c * 32 + w * 8 + (lane >> 3);
    scol[c] = ((lane & 7) ^ (srow[c] & 7)) << 3;   // inverse swizzle on source
  }

  f32x4 z = {0.f, 0.f, 0.f, 0.f};
  f32x4 acc[4][4];
#pragma unroll
  for (int i = 0; i < 4; ++i)
#pragma unroll
    for (int j = 0; j < 4; ++j) acc[i][j] = z;

  unsigned short* Af0 = &As[0][0][0];
  unsigned short* Bf0 = &Bs[0][0][0];
  const int cb = 16 * (lane >> 4);   // byte offset of k-slice within row

#define STAGE_G(buf, k0) do {                                                          \
    unsigned short* Ad = Af0 + (buf) * 8192 + w * 512;                                 \
    unsigned short* Bd = Bf0 + (buf) * 8192 + w * 512;                                 \
    _Pragma("unroll")                                                                  \
    for (int c = 0; c < 4; ++c) {                                                      \
      gload16(A  + (size_t)(R0 + srow[c]) * DM + (k0) + scol[c], Ad + c * 2048);       \
      gload16(Bw + (size_t)(C0 + srow[c]) * DM + (k0) + scol[c], Bd + c * 2048);       \
    }                                                                                  \
  } while (0)

  STAGE_G(0, 0);
  __syncthreads();

  for (int t = 0; t < 16; ++t) {
    const int cur = t & 1;
    if (t + 1 < 16) STAGE_G(cur ^ 1, (t + 1) * 64);

    const char* Af = (const char*)(Af0 + cur * 8192);
    const char* Bf = (const char*)(Bf0 + cur * 8192);
    bf16x8 av[4][2], bv[4][2];
#pragma unroll
    for (int i = 0; i < 4; ++i) {
      int row = 64 * wr + 16 * i + (lane & 15);
      int sw = (row & 7) << 4;
      const char* rp = Af + row * 128;
      av[i][0] = *(const bf16x8*)(rp + (cb ^ sw));
      av[i][1] = *(const bf16x8*)(rp + ((cb + 64) ^ sw));
    }
#pragma unroll
    for (int j = 0; j < 4; ++j) {
      int row = 64 * wc + 16 * j + (lane & 15);
      int sw = (row & 7) << 4;
      const char* rp = Bf + row * 128;
      bv[j][0] = *(const bf16x8*)(rp + (cb ^ sw));
      bv[j][1] = *(const bf16x8*)(rp + ((cb + 64) ^ sw));
    }
    if (swap) {
#pragma unroll
      for (int i = 0; i < 4; ++i)
#pragma unroll
        for (int j = 0; j < 4; ++j) {
          acc[i][j] = __builtin_amdgcn_mfma_f32_16x16x32_bf16(bv[j][0], av[i][0], acc[i][j], 0, 0, 0);
          acc[i][j] = __builtin_amdgcn_mfma_f32_16x16x32_bf16(bv[j][1], av[i][1], acc[i][j], 0, 0, 0);
        }
    } else {
#pragma unroll
      for (int i = 0; i < 4; ++i)
#pragma unroll
        for (int j = 0; j < 4; ++j) {
          acc[i][j] = __builtin_amdgcn_mfma_f32_16x16x32_bf16(av[i][0], bv[j][0], acc[i][j], 0, 0, 0);
          acc[i][j] = __builtin_amdgcn_mfma_f32_16x16x32_bf16(av[i][1], bv[j][1], acc[i][j], 0, 0, 0);
        }
    }
    __syncthreads();   // drains vmcnt (next stage) + protects LDS
  }
#undef STAGE_G

  float s = 0.f;
#pragma unroll
  for (int i = 0; i < 4; ++i) {
#pragma unroll
    for (int j = 0; j < 4; ++j) {
      if (swap) {
        int grow  = R0 + 64 * wr + 16 * i + (lane & 15);
        int gcol0 = C0 + 64 * wc + 16 * j + 4 * (lane >> 4);
        if (omode == 0) {
          float4 st = {acc[i][j][0] * oscale, acc[i][j][1] * oscale,
                       acc[i][j][2] * oscale, acc[i][j][3] * oscale};
          s += fabsf(st.x) + fabsf(st.y) + fabsf(st.z) + fabsf(st.w);
          *(float4*)((float*)Cptr + (size_t)grow * DM + gcol0) = st;
        } else {
          int b = grow >> 11, ss = grow & (S_LEN - 1);
          int h = gcol0 >> 6, d0 = gcol0 & 63;
          ushort4 st = {f2bf(acc[i][j][0] * oscale), f2bf(acc[i][j][1] * oscale),
                        f2bf(acc[i][j][2] * oscale), f2bf(acc[i][j][3] * oscale)};
          *(ushort4*)((unsigned short*)Cptr + (((size_t)(b * NH + h) * S_LEN + ss) << 6) + d0) = st;
        }
      } else {
        int grow0 = R0 + 64 * wr + 16 * i + 4 * (lane >> 4);
        int gcol  = C0 + 64 * wc + 16 * j + (lane & 15);
        int b = grow0 >> 11, s0 = grow0 & (S_LEN - 1);
        int h = gcol >> 6, d = gcol & 63;
        ushort4 st = {f2bf(acc[i][j][0] * oscale), f2bf(acc[i][j][1] * oscale),
                      f2bf(acc[i][j][2] * oscale), f2bf(acc[i][j][3] * oscale)};
        *(ushort4*)((unsigned short*)Cptr + (((size_t)(b * NH + h) * DH + d) << 11) + s0) = st;
      }
    }
  }
  if (partials) {   // deterministic per-block |x| partial (fused abspart)
#pragma unroll
    for (int mk = 1; mk < 64; mk <<= 1) s += __shfl_xor(s, mk, 64);
    if (lane == 0) red[w] = s;
    __syncthreads();
    if (tid == 0) partials[pbid] = red[0] + red[1] + red[2] + red[3];
  }
}

// merged QKV: z selects operand set at runtime (one body -> one 64KB LDS; 768 blocks)
__global__ __launch_bounds__(256) void k_gemm_qkv(const unsigned short* __restrict__ qb,
                                                  const unsigned short* __restrict__ kb,
                                                  const unsigned short* __restrict__ vb,
                                                  const unsigned short* __restrict__ WbQ,
                                                  const unsigned short* __restrict__ WbK,
                                                  const unsigned short* __restrict__ WbV,
                                                  unsigned short* __restrict__ qh,
                                                  unsigned short* __restrict__ kh,
                                                  unsigned short* __restrict__ vt) {
  const unsigned short *A, *B;
  unsigned short* C;
  float sc;
  int om;
  bool sw;
  if (blockIdx.z == 0)      { A = qb; B = WbQ; C = qh; sc = 0.125f; om = 1; sw = true;  }
  else if (blockIdx.z == 1) { A = kb; B = WbK; C = kh; sc = 1.0f;   om = 1; sw = true;  }
  else                      { A = vb; B = WbV; C = vt; sc = 1.0f;   om = 2; sw = false; }
  gemm128_core(A, B, C, sc, om, sw, blockIdx.x * 128, blockIdx.y * 128, nullptr, 0);
}

__global__ __launch_bounds__(256) void k_gemm_out(const unsigned short* __restrict__ A,
                                                  const unsigned short* __restrict__ Bw,
                                                  float* __restrict__ C,
                                                  float* __restrict__ partials) {
  gemm128_core(A, Bw, C, 1.0f, 0, true, blockIdx.x * 128, blockIdx.y * 128,
               partials, blockIdx.x + gridDim.x * blockIdx.y);
}

// ---------------- full-matrix |scores| max (before masking) ----------------
// grid: (S/128, B*H). Q tile (128 rows) in registers; K chunks double-buffered via gload16+swizzle.
__global__ __launch_bounds__(256) void k_scoresmax(const unsigned short* __restrict__ qh,
                                                   const unsigned short* __restrict__ kh,
                                                   unsigned int* __restrict__ absmax) {
  __shared__ unsigned short Ks[2][128][64];
  const int tid = threadIdx.x, lane = tid & 63, w = tid >> 6;
  const size_t base = (size_t)blockIdx.y * S_LEN * DH;
  const unsigned short* Q = qh + base;
  const unsigned short* K = kh + base;
  const int q0 = blockIdx.x * 128;

  bf16x8 a[2][2];
#pragma unroll
  for (int rb = 0; rb < 2; ++rb) {
    const unsigned short* qr = Q + (size_t)(q0 + 32 * w + 16 * rb + (lane & 15)) * DH + 8 * (lane >> 4);
    a[rb][0] = *(const bf16x8*)qr;
    a[rb][1] = *(const bf16x8*)(qr + 32);
  }

  int srow[4], scol[4];
#pragma unroll
  for (int c = 0; c < 4; ++c) {
    srow[c] = c * 32 + w * 8 + (lane >> 3);
    scol[c] = ((lane & 7) ^ (srow[c] & 7)) << 3;
  }
  unsigned short* Kf0 = &Ks[0][0][0];
  const int cbb = 16 * (lane >> 4);

#define STAGE_K(buf, kc) do {                                                          \
    unsigned short* Kd = Kf0 + (buf) * 8192 + w * 512;                                 \
    _Pragma("unroll")                                                                  \
    for (int c = 0; c < 4; ++c)                                                        \
      gload16(K + (size_t)((kc) + srow[c]) * DH + scol[c], Kd + c * 2048);             \
  } while (0)

  STAGE_K(0, 0);
  __syncthreads();

  float m = 0.f;
  for (int t = 0; t < 16; ++t) {
    const int cur = t & 1;
    if (t + 1 < 16) STAGE_K(cur ^ 1, (t + 1) * 128);
    const char* Kf = (const char*)(Kf0 + cur * 8192);
#pragma unroll
    for (int cb = 0; cb < 8; ++cb) {
      int row = 16 * cb + (lane & 15);
      int sw = (row & 7) << 4;
      const char* rp = Kf + row * 128;
      bf16x8 b0 = *(const bf16x8*)(rp + (cbb ^ sw));
      bf16x8 b1 = *(const bf16x8*)(rp + ((cbb + 64) ^ sw));
#pragma unroll
      for (int rb = 0; rb < 2; ++rb) {
        f32x4 acc = {0.f, 0.f, 0.f, 0.f};
        acc = __builtin_amdgcn_mfma_f32_16x16x32_bf16(a[rb][0], b0, acc, 0, 0, 0);
        acc = __builtin_amdgcn_mfma_f32_16x16x32_bf16(a[rb][1], b1, acc, 0, 0, 0);
        m = fmaxf(m, fmaxf(fmaxf(fabsf(acc[0]), fabsf(acc[1])), fmaxf(fabsf(acc[2]), fabsf(acc[3]))));
      }
    }
    __syncthreads();
  }
#undef STAGE_K

#pragma unroll
  for (int mk = 1; mk < 64; mk <<= 1) m = fmaxf(m, __shfl_xor(m, mk, 64));
  __shared__ float red[4];
  if (lane == 0) red[w] = m;
  __syncthreads();
  if (threadIdx.x == 0)
    atomicMax(absmax, __float_as_uint(fmaxf(fmaxf(red[0], red[1]), fmaxf(red[2], red[3]))));
}

// ---------------- sliding-window attention, streaming 32-key tiles ----------------
// grid: (S/64, B*H). 4 waves; wave w owns q rows [Q0+16w, Q0+16w+15].
// Scores*invM are in [-1,1] -> no softmax max pass needed (exp() directly, masked -> 0).
// V comes pre-transposed: vt[b,h,d,s].
#define NT 10
__global__ __launch_bounds__(256) void k_attn(const unsigned short* __restrict__ qh,
                                              const unsigned short* __restrict__ kh,
                                              const unsigned short* __restrict__ vt,
                                              const unsigned int* __restrict__ absmax,
                                              unsigned short* __restrict__ attn_c) {
  __shared__ unsigned short Ks[2][32][72];    // 9216 B   K tile: [key][d]
  __shared__ unsigned short Vts[2][64][40];   // 10240 B  Vt tile: [d][key]
  __shared__ unsigned short Pl[4][16][40];    // 5120 B   per-wave P redistribution (80B row stride, b128-aligned)
  const int tid = threadIdx.x, lane = tid & 63, w = tid >> 6;
  const int bh = blockIdx.y, b = bh >> 4, h = bh & 15;
  const int Q0 = blockIdx.x * 64;
  const int kstart = Q0 - WIN;
  const size_t base = (size_t)bh * S_LEN * DH;
  const unsigned short* Kb = kh + base;
  const unsigned short* Vtb = vt + base;      // [d][s] rows of length S_LEN

  // staging coords (one ushort8 per thread per buffer)
  const int skrow = tid >> 3, skcol = (tid & 7) << 3;     // K: 32 rows x 64 d
  const int svd = tid >> 2, svcol = (tid & 3) << 3;       // Vt: 64 d x 32 keys

  const float invM = 1.0f / fmaxf(__uint_as_float(*absmax), 1.0f);
  const unsigned short* Qp = qh + base + (size_t)(Q0 + 16 * w + (lane & 15)) * DH + 8 * (lane >> 4);
  bf16x8 a0 = *(const bf16x8*)Qp;
  bf16x8 a1 = *(const bf16x8*)(Qp + 32);

  ushort8 rk, rv;
  ushort8 zz = {0, 0, 0, 0, 0, 0, 0, 0};
#define LOADT(T) do {                                                        \
    int kk = kstart + 32 * (T) + skrow;                                      \
    rk = (kk >= 0) ? *(const ushort8*)(Kb + (size_t)kk * DH + skcol) : zz;   \
    int kc = kstart + 32 * (T) + svcol;                                      \
    rv = (kc >= 0) ? *(const ushort8*)(Vtb + (size_t)svd * S_LEN + kc) : zz; \
  } while (0)
#define WRITET(buf) do {                                                     \
    *(ushort8*)&Ks[buf][skrow][skcol] = rk;                                  \
    *(ushort8*)&Vts[buf][svd][svcol] = rv;                                   \
  } while (0)

  LOADT(0);
  WRITET(0);
  __syncthreads();

  const int Tlo = w >> 1, Thi = (w >> 1) + 8;
  const int qrow = Q0 + 16 * w + 4 * (lane >> 4);
  float sm[4] = {0.f, 0.f, 0.f, 0.f};
  f32x4 z = {0.f, 0.f, 0.f, 0.f};
  f32x4 o[4];
#pragma unroll
  for (int i = 0; i < 4; ++i) o[i] = z;

  for (int T = 0; T < NT; ++T) {
    const int cur = T & 1;
    const bool act = (T >= Tlo) && (T <= Thi);
    if (T + 1 < NT) LOADT(T + 1);            // issue next-tile loads early
    if (act) {
      // QK^T: 32 keys, 2 col-blocks
      f32x4 p[2];
#pragma unroll
      for (int cb = 0; cb < 2; ++cb) {
        const unsigned short* kr = &Ks[cur][16 * cb + (lane & 15)][8 * (lane >> 4)];
        bf16x8 b0 = *(const bf16x8*)kr;
        bf16x8 b1 = *(const bf16x8*)(kr + 32);
        f32x4 a = z;
        a = __builtin_amdgcn_mfma_f32_16x16x32_bf16(a0, b0, a, 0, 0, 0);
        a = __builtin_amdgcn_mfma_f32_16x16x32_bf16(a1, b1, a, 0, 0, 0);
        p[cb] = a;
      }
      // mask + exp (no max needed: |s|<=1) + accumulate denominator + stash P
#pragma unroll
      for (int cb = 0; cb < 2; ++cb) {
        int kcol = kstart + 32 * T + 16 * cb + (lane & 15);
#pragma unroll
        for (int r = 0; r < 4; ++r) {
          int qq = qrow + r;
          bool ok = (kcol >= 0) && (kcol <= qq) && (kcol + WIN > qq);
          float e = ok ? __expf(p[cb][r] * invM) : 0.f;
          sm[r] += e;
          Pl[w][4 * (lane >> 4) + r][16 * cb + (lane & 15)] = f2bf(e);
        }
      }
    }
    __syncthreads();                         // Pl writes visible before A-frag read
    if (act) {
      // PV: one A-frag covers all 32 keys
      bf16x8 pa = *(const bf16x8*)&Pl[w][lane & 15][8 * (lane >> 4)];
#pragma unroll
      for (int dt = 0; dt < 4; ++dt) {
        bf16x8 bv = *(const bf16x8*)&Vts[cur][16 * dt + (lane & 15)][8 * (lane >> 4)];
        o[dt] = __builtin_amdgcn_mfma_f32_16x16x32_bf16(pa, bv, o[dt], 0, 0, 0);
      }
    }
    if (T + 1 < NT) WRITET((T + 1) & 1);     // write next tile into the other buffer
    __syncthreads();
  }

  // reduce denominator across the 16 column-lanes of each row group
#pragma unroll
  for (int r = 0; r < 4; ++r) {
#pragma unroll
    for (int mk = 1; mk < 16; mk <<= 1) sm[r] += __shfl_xor(sm[r], mk, 64);
    sm[r] = 1.0f / sm[r];
  }
#pragma unroll
  for (int dt = 0; dt < 4; ++dt) {
#pragma unroll
    for (int r = 0; r < 4; ++r) {
      int qq = qrow + r;
      float val = o[dt][r] * sm[r];
      attn_c[((size_t)(b * S_LEN + qq) << 10) + h * DH + 16 * dt + (lane & 15)] = f2bf(val);
    }
  }
#undef LOADT
#undef WRITET
}

// ---------------- final: denom from partials (every block, deterministic) + scale ----------------
__global__ __launch_bounds__(256) void k_scale_final(float* __restrict__ x,
                                                     const float* __restrict__ partials,
                                                     float invcnt, int n4) {
  __shared__ float red[4];
  float s = partials[threadIdx.x];           // blockDim == #partials == 256
#pragma unroll
  for (int mk = 1; mk < 64; mk <<= 1) s += __shfl_xor(s, mk, 64);
  if ((threadIdx.x & 63) == 0) red[threadIdx.x >> 6] = s;
  __syncthreads();
  float d = 1.0f / fmaxf((red[0] + red[1] + red[2] + red[3]) * invcnt, 1.0f);
  for (int i = blockIdx.x * blockDim.x + threadIdx.x; i < n4; i += gridDim.x * blockDim.x) {
    float4 f = ((float4*)x)[i];
    f.x *= d; f.y *= d; f.z *= d; f.w *= d;
    ((float4*)x)[i] = f;
  }
}

// ---------------- launch ----------------
extern "C" void kernel_launch(void* const* d_in, const int* in_sizes, int n_in,
                              void* d_out, int out_size, void* d_ws, size_t ws_size,
                              hipStream_t stream) {
  (void)in_sizes; (void)n_in; (void)out_size; (void)ws_size;
  const float* q  = (const float*)d_in[0];
  const float* k  = (const float*)d_in[1];
  const float* v  = (const float*)d_in[2];
  const float* WQ = (const float*)d_in[3];
  const float* WK = (const float*)d_in[4];
  const float* WV = (const float*)d_in[5];
  const float* WO = (const float*)d_in[6];

  const size_t HS = (size_t)BATCH * NH * S_LEN * DH;     // 4,194,304 elements
  unsigned short* qb     = (unsigned short*)d_ws;        // bf16 q input; reused as attn_c later
  unsigned short* kb     = qb + HS;
  unsigned short* vb     = kb + HS;
  unsigned short* qh     = vb + HS;
  unsigned short* kh     = qh + HS;
  unsigned short* vt     = kh + HS;                      // [b,h,d,s] bf16
  unsigned short* Wb     = vt + HS;                      // 4 x 1M bf16
  char* scal             = (char*)(Wb + 4 * (size_t)DM * DM);
  unsigned int* absmax   = (unsigned int*)scal;
  float* partials        = (float*)(scal + 16);          // 256 entries
  unsigned short* attn_c = qb;                           // alias: qb dead after QKV GEMM

  unsigned short* WbQ = Wb;
  unsigned short* WbK = Wb + (size_t)DM * DM;
  unsigned short* WbV = Wb + 2 * (size_t)DM * DM;
  unsigned short* WbO = Wb + 3 * (size_t)DM * DM;

  k_cvt_all<<<dim3(128, 1, 7), 256, 0, stream>>>(WQ, WK, WV, WO, q, k, v, Wb, qb, kb, vb, absmax);

  k_gemm_qkv<<<dim3(32, 8, 3), 256, 0, stream>>>(qb, kb, vb, WbQ, WbK, WbV, qh, kh, vt);

  k_scoresmax<<<dim3(16, 32), 256, 0, stream>>>(qh, kh, absmax);
  k_attn<<<dim3(32, 32), 256, 0, stream>>>(qh, kh, vt, absmax, attn_c);

  k_gemm_out<<<dim3(32, 8), 256, 0, stream>>>(attn_c, WbO, (float*)d_out, partials);

  k_scale_final<<<1024, 256, 0, stream>>>((float*)d_out, partials, 1.0f / (float)HS, (int)(HS / 4));
}